// Round 13
// baseline (276.554 us; speedup 1.0000x reference)
//
#include <hip/hip_runtime.h>
#include <hip/hip_fp16.h>

#define U_N 50000
#define I_N 100000
#define E_N 1600000
#define B_N 16384
#define UI_N (U_N + I_N)   // 150000
#define NB_U 782           // ceil(50000/64)
#define NB_I 1563          // ceil(100000/64)
#define NBK 586            // ceil(150000/256) buckets, 256 nodes each
#define CAP 16384          // padded entries per bucket
#define NBLD 256           // blocks in k_build1 (proven round-5/9 config)
#define CHUNK (E_N / NBLD) // 6250 edges per block
#define COL_CAP 3300000    // compact col (exact 3.2M + margin)
#define MAXACT 32768       // max unique dot nodes
#define FP8_SCALE 128.0f
#define LOG2E 1.44269504088896f

typedef float f32x2 __attribute__((ext_vector_type(2)));

// ---------------- CSR build phase 1: LDS counting-sort + full-line burst writes -------
__global__ __launch_bounds__(1024) void k_build1(
    const int* __restrict__ eu, const int* __restrict__ ei,
    int* __restrict__ bcnt, int* __restrict__ ecnt, int* __restrict__ storage) {
  __shared__ int hist[NBK];
  __shared__ int pb16[NBK];
  __shared__ int gbase[NBK];
  __shared__ int loff[NBK];
  __shared__ short map16[1344];
  __shared__ int sc[1024];
  __shared__ int sorted[21504];
  int t = threadIdx.x;
  for (int b = t; b < NBK; b += 1024) { hist[b] = 0; loff[b] = 0; }
  __syncthreads();
  int e0 = blockIdx.x * CHUNK;
  int myu[7], myi[7];
#pragma unroll
  for (int k = 0; k < 7; k++) {
    myu[k] = -1;
    if (t + 1024 * k < CHUNK) {
      int e = e0 + t + 1024 * k;
      int u = eu[e], it = ei[e];
      myu[k] = u;
      myi[k] = it;
      atomicAdd(&hist[u >> 8], 1);
      atomicAdd(&hist[(U_N + it) >> 8], 1);
    }
  }
  __syncthreads();
  int ph = (t < NBK) ? ((hist[t] + 15) & ~15) : 0;
  sc[t] = ph;
  __syncthreads();
  int val = ph;
  for (int o = 1; o < 1024; o <<= 1) {
    int x = (t >= o) ? sc[t - o] : 0;
    __syncthreads();
    val += x;
    sc[t] = val;
    __syncthreads();
  }
  int total16 = sc[1023];
  if (t < NBK) {
    int myb = val - ph;
    pb16[t] = myb;
    gbase[t] = ph ? atomicAdd(&bcnt[t], ph) : 0;
    if (hist[t]) atomicAdd(&ecnt[t], hist[t]);
    for (int k = myb >> 4; k < (myb + ph) >> 4; k++) map16[k] = (short)t;
  }
  for (int j = t; j < total16; j += 1024) sorted[j] = -1;
  __syncthreads();
#pragma unroll
  for (int k = 0; k < 7; k++) {
    if (myu[k] >= 0) {
      int u = myu[k], it = myi[k];
      int k2 = U_N + it;
      int b1 = u >> 8;
      int p1 = pb16[b1] + atomicAdd(&loff[b1], 1);
      sorted[p1] = ((u & 255) << 18) | k2;
      int b2 = k2 >> 8;
      int p2 = pb16[b2] + atomicAdd(&loff[b2], 1);
      sorted[p2] = ((k2 & 255) << 18) | u;
    }
  }
  __syncthreads();
  for (int j = t; j < total16; j += 1024) {
    int b = map16[j >> 4];
    storage[(size_t)b * CAP + gbase[b] + (j - pb16[b])] = sorted[j];
  }
}

// ---- CSR build phase 2: count (skip sentinels) -> LDS prefix -> LDS-staged scatter
//      -> coalesced burst copy to global col (round-5/9 proven) ----
__device__ void build2_body(int b, const int* __restrict__ bcnt,
                            const int* __restrict__ ecnt,
                            const int* __restrict__ storage,
                            int* __restrict__ ptr, int* __restrict__ col,
                            int* smem) {
  int* c = smem;            // [256]
  int* sc = smem + 256;     // [256]
  int* pbl = smem + 512;    // [256]
  int* cur = smem + 768;    // [256]
  int* tot = smem + 1024;   // [1]
  int* lcol = smem + 1040;  // [10240]
  int t = threadIdx.x;
  int pre = 0;
  for (int i = t; i < b; i += 256) pre += ecnt[i];
  sc[t] = pre;
  c[t] = 0;
  __syncthreads();
  for (int o = 128; o > 0; o >>= 1) {
    if (t < o) sc[t] += sc[t + o];
    __syncthreads();
  }
  int base = sc[0];
  __syncthreads();
  int n = bcnt[b];
  const int* s = storage + (size_t)b * CAP;
  for (int i = t; i < n; i += 256) {
    int e = s[i];
    if (e >= 0) atomicAdd(&c[e >> 18], 1);
  }
  __syncthreads();
  int deg = c[t];
  sc[t] = deg;
  __syncthreads();
  int val = deg;
  for (int o = 1; o < 256; o <<= 1) {
    int x = (t >= o) ? sc[t - o] : 0;
    __syncthreads();
    val += x;
    sc[t] = val;
    __syncthreads();
  }
  int myoff = val - deg;
  pbl[t] = myoff;
  cur[t] = 0;
  if (t == 255) tot[0] = val;
  int node = b * 256 + t;
  if (node < UI_N) ptr[node] = base + myoff;
  if (b == NBK - 1 && t == 255) ptr[UI_N] = base + val;
  __syncthreads();
  for (int i = t; i < n; i += 256) {
    int e = s[i];
    if (e >= 0) {
      int local = e >> 18;
      int pos = pbl[local] + atomicAdd(&cur[local], 1);
      lcol[pos] = e & 0x3FFFF;
    }
  }
  __syncthreads();
  int vt = tot[0];
  for (int i = t; i < vt; i += 256) col[base + i] = lcol[i];
}

// ---------------- active-node flag + compaction body ----------------
__device__ __forceinline__ void flagc_body(int bid, const int* __restrict__ uIdx,
                                           const int* __restrict__ iIdx,
                                           int* __restrict__ flag, int* __restrict__ list,
                                           int* __restrict__ nm) {
  int b = bid * 256 + threadIdx.x;
  if (b < B_N) {
    int u = uIdx[b];
    if (atomicExch(&flag[u], 1) == 0) list[atomicAdd(nm, 1)] = u;
    int it = U_N + iIdx[b];
    if (atomicExch(&flag[it], 1) == 0) list[atomicAdd(nm, 1)] = it;
  }
}

// ---------------- Fused matmul + attention scores body (fp16 + fp8 outputs) ----------
// Scores stored pre-scaled by log2(e) -> agg uses bare exp2 per edge.
__device__ __forceinline__ void mm2_body(
    int bid, const float* __restrict__ Xu32, const float* __restrict__ Xi32,
    const __half* __restrict__ X16,
    const float* __restrict__ Wu, const float* __restrict__ Wi,
    const float* __restrict__ a, int layer,
    __half* __restrict__ f16, unsigned char* __restrict__ f8,
    __half* __restrict__ s16, const int* __restrict__ flagp,
    float* Wl, float* Xs) {
  const bool isU = bid < NB_U;
  const int N = isU ? U_N : I_N;
  const int base = (isU ? bid : bid - NB_U) * 64;
  const int gofs = isU ? 0 : U_N;
  const float* W = isU ? Wu : Wi;
  const int aoff = (layer == 1) ? (isU ? 0 : 8) : (isU ? 0 : 64);
  int t = threadIdx.x;

  if (layer == 1) {
#pragma unroll
    for (int k = 0; k < 4; k++) {
      int i = t + 256 * k;
      int h = i >> 7, d = (i >> 1) & 63, half = i & 1;
      float4 v = *(const float4*)(W + h * 512 + d * 8 + half * 4);
      *(float4*)(Wl + d * 64 + h * 8 + half * 4) = v;
    }
    const float* X = isU ? Xu32 : Xi32;
#pragma unroll
    for (int k = 0; k < 4; k++) {
      int i = t + 256 * k;
      int r = i >> 4, ch = i & 15;
      int node = base + r;
      float4 v = make_float4(0.f, 0.f, 0.f, 0.f);
      if (node < N) v = *(const float4*)(X + (size_t)node * 64 + ch * 4);
      *(float4*)(Xs + r * 64 + ch * 4) = v;
    }
  } else {
#pragma unroll
    for (int k = 0; k < 4; k++) {
      int i = t + 256 * k;
      *(float4*)(Wl + i * 4) = *(const float4*)(W + i * 4);
    }
#pragma unroll
    for (int k = 0; k < 4; k++) {
      int i = t + 256 * k;
      int r = i >> 4, ch = i & 15;
      int node = base + r;
      float4 v = make_float4(0.f, 0.f, 0.f, 0.f);
      if (node < N) {
        const __half2* hp = (const __half2*)(X16 + (size_t)(gofs + node) * 64 + ch * 4);
        float2 f0 = __half22float2(hp[0]);
        float2 f1 = __half22float2(hp[1]);
        v = make_float4(f0.x, f0.y, f1.x, f1.y);
      }
      *(float4*)(Xs + r * 64 + ch * 4) = v;
    }
  }
  __syncthreads();

  const int c0 = t & 31;
  const int rb = t >> 5;
  float acc0[8], acc1[8];
#pragma unroll
  for (int k = 0; k < 8; k++) { acc0[k] = 0.f; acc1[k] = 0.f; }

  for (int d0 = 0; d0 < 64; d0 += 4) {
    float2 wA = *(float2*)(Wl + (d0 + 0) * 64 + 2 * c0);
    float2 wB = *(float2*)(Wl + (d0 + 1) * 64 + 2 * c0);
    float2 wC = *(float2*)(Wl + (d0 + 2) * 64 + 2 * c0);
    float2 wD = *(float2*)(Wl + (d0 + 3) * 64 + 2 * c0);
#pragma unroll
    for (int k = 0; k < 8; k++) {
      float4 x = *(float4*)(Xs + (rb + 8 * k) * 64 + d0);
      acc0[k] += x.x * wA.x + x.y * wB.x + x.z * wC.x + x.w * wD.x;
      acc1[k] += x.x * wA.y + x.y * wB.y + x.z * wC.y + x.w * wD.y;
    }
  }

  float av0, av1;
  if (layer == 1) {
    int h = c0 >> 2, j = 2 * (c0 & 3);
    av0 = a[h * 16 + aoff + j];
    av1 = a[h * 16 + aoff + j + 1];
  } else {
    av0 = a[aoff + 2 * c0];
    av1 = a[aoff + 2 * c0 + 1];
  }
#pragma unroll
  for (int k = 0; k < 8; k++) {
    int node = base + rb + 8 * k;
    float s = acc0[k] * av0 + acc1[k] * av1;
    s += __shfl_xor(s, 1);
    s += __shfl_xor(s, 2);
    if (layer != 1) {
      s += __shfl_xor(s, 4);
      s += __shfl_xor(s, 8);
      s += __shfl_xor(s, 16);
    }
    if (node < N) {
      int gn = gofs + node;
      if (layer == 1 || flagp[gn]) {
        float2 f;
        f.x = acc0[k];
        f.y = acc1[k];
        *(__half2*)(f16 + (size_t)gn * 64 + 2 * c0) = __float22half2_rn(f);
      }
      int pk = __builtin_amdgcn_cvt_pk_fp8_f32(acc0[k] * FP8_SCALE,
                                               acc1[k] * FP8_SCALE, 0, false);
      *(unsigned short*)(f8 + (size_t)gn * 64 + 2 * c0) = (unsigned short)pk;
      if (layer == 1) {
        if ((c0 & 3) == 0) s16[gn * 8 + (c0 >> 2)] = __float2half_rn(s * LOG2E);
      } else {
        if (c0 == 0) s16[gn] = __float2half_rn(s * LOG2E);
      }
    }
  }
}

// ---- Fused dispatch: build2 (+count) | flagc | mm2-L1, all 256-thread blocks ---------
__global__ __launch_bounds__(256) void k_fused2(
    const int* __restrict__ bcnt, const int* __restrict__ ecnt,
    const int* __restrict__ storage,
    int* __restrict__ ptr, int* __restrict__ col,
    const int* __restrict__ uIdx, const int* __restrict__ iIdx,
    int* __restrict__ flag, int* __restrict__ list, int* __restrict__ nm,
    const float* __restrict__ uEmbd, const float* __restrict__ iEmbd,
    const float* __restrict__ Wu, const float* __restrict__ Wi,
    const float* __restrict__ a, __half* __restrict__ fA,
    unsigned char* __restrict__ fA8, __half* __restrict__ s16) {
  __shared__ __align__(16) int smem_i[11296];  // 45.2KB: build2 stage / mm 8192 floats
  int bx = blockIdx.x;
  if (bx < NBK) {
    build2_body(bx, bcnt, ecnt, storage, ptr, col, smem_i);
  } else if (bx < NBK + 64) {
    flagc_body(bx - NBK, uIdx, iIdx, flag, list, nm);
  } else {
    float* s = (float*)smem_i;
    mm2_body(bx - NBK - 64, uEmbd, iEmbd, nullptr, Wu, Wi, a, 1, fA, fA8, s16,
             nullptr, s, s + 4096);
  }
}

// ---------------- Layer-2 matmul (standalone) ----------------
__global__ __launch_bounds__(256) void k_mm2(
    const __half* __restrict__ X16, const float* __restrict__ Wu,
    const float* __restrict__ Wi, const float* __restrict__ a,
    __half* __restrict__ f16, unsigned char* __restrict__ f8,
    __half* __restrict__ s2, const int* __restrict__ flag) {
  __shared__ __align__(16) float smv[8192];
  mm2_body(blockIdx.x, nullptr, nullptr, X16, Wu, Wi, a, 2, f16, f8, s2, flag,
           smv, smv + 4096);
}

// ---------------- Fused aggregation: TWO nodes/wave + 2-deep software pipeline -------
// Measured (R12): ~10800 cyc/wave ≈ serial col->gather latency per 16-edge quad; only
// ONE gather batch in flight per wave. Fix: named A/B register sets, PRE(S) issues the
// next quad's col+score+f8 loads BEFORE consuming the current quad -> 2 batches in
// flight, per-quad critical path ~halved. Epilogue fA self-row prefetched pre-loop.
template <int LAYER>
__device__ __forceinline__ void agg_body(
    const int* __restrict__ ptr, const int* __restrict__ col,
    const unsigned char* __restrict__ f8,  // [UI_N][64] e4m3 x128
    const __half* __restrict__ fA,         // [UI_N][64] fp16 (self)
    __half* __restrict__ fB,               // [UI_N][64]
    const __half* __restrict__ sc,         // L1: [UI_N][8] (xlog2e); L2: [UI_N] (xlog2e)
    const int* __restrict__ list, const int* __restrict__ nm) {
  int gid = blockIdx.x * blockDim.x + threadIdx.x;
  int wv = gid >> 6;
  int l = threadIdx.x & 63;
  int half = l >> 5;
  int idx = wv * 2 + half;
  bool act = true;
  int n;
  if (LAYER == 2) {
    act = idx < *nm;
    n = act ? list[idx] : 0;
  } else {
    n = idx;
  }
  int lh = l & 31;
  int g = lh >> 3;
  int cc = lh & 7;

  int beg = ptr[n], endA = ptr[n + 1];
  int deg = act ? (endA - beg) : 0;
  unsigned coff = ((unsigned)(beg + g)) << 2;
  const unsigned begb = (unsigned)beg << 2;
  const unsigned f8sh = (unsigned)cc << 3;
  const unsigned ssh = (LAYER == 1) ? ((unsigned)cc << 1) : 0u;
  float sself = (LAYER == 1) ? __half2float(sc[(size_t)n * 8 + cc])
                             : __half2float(sc[n]);
  // epilogue self-row prefetch (issued now, consumed after the loop)
  size_t boff = (size_t)n * 64 + cc * 8 + 2 * g;
  __half2 selfh = *(const __half2*)(fA + boff);

  f32x2 acc2[4];
#pragma unroll
  for (int k = 0; k < 4; k++) acc2[k] = (f32x2){0.f, 0.f};
  float wsum = 0.f;
  const char* colc = (const char*)col;
  const char* f8c = (const char*)f8;
  const char* scc = (const char*)sc;

#define LDSC(nb) ((LAYER == 1) ? *(const __half*)(scc + (((unsigned)(nb) << 4) + ssh)) \
                               : *(const __half*)(scc + ((unsigned)(nb) << 1)))
#define LDF8(nb) (*(const int2*)(f8c + (((unsigned)(nb) << 6) + f8sh)))

  int nbA0, nbA1, nbA2, nbA3, nbB0, nbB1, nbB2, nbB3;
  __half sA0, sA1, sA2, sA3, sB0, sB1, sB2, sB3;
  int2 rA0, rA1, rA2, rA3, rB0, rB1, rB2, rB3;

#define PRE(S) do { \
    nb##S##0 = *(const int*)(colc + coff); \
    nb##S##1 = *(const int*)(colc + coff + 16); \
    nb##S##2 = *(const int*)(colc + coff + 32); \
    nb##S##3 = *(const int*)(colc + coff + 48); \
    s##S##0 = LDSC(nb##S##0); r##S##0 = LDF8(nb##S##0); \
    s##S##1 = LDSC(nb##S##1); r##S##1 = LDF8(nb##S##1); \
    s##S##2 = LDSC(nb##S##2); r##S##2 = LDF8(nb##S##2); \
    s##S##3 = LDSC(nb##S##3); r##S##3 = LDF8(nb##S##3); \
    coff += 64; \
  } while (0)

#define ACC1(sv, rv) do { \
    float x_ = sself + __half2float(sv); \
    float w_ = exp2f(-fmaxf(x_, 0.2f * x_)); \
    wsum += w_; \
    f32x2 w2_ = {w_, w_}; \
    acc2[0] += w2_ * __builtin_amdgcn_cvt_pk_f32_fp8((unsigned)(rv).x, false); \
    acc2[1] += w2_ * __builtin_amdgcn_cvt_pk_f32_fp8((unsigned)(rv).x, true); \
    acc2[2] += w2_ * __builtin_amdgcn_cvt_pk_f32_fp8((unsigned)(rv).y, false); \
    acc2[3] += w2_ * __builtin_amdgcn_cvt_pk_f32_fp8((unsigned)(rv).y, true); \
  } while (0)

#define CONSUME(S) do { ACC1(s##S##0, r##S##0); ACC1(s##S##1, r##S##1); \
                        ACC1(s##S##2, r##S##2); ACC1(s##S##3, r##S##3); } while (0)

  int q = deg >> 4;
  if (q > 0) {
    PRE(A); q--;
    bool aLive = true;
    while (q > 0) {
      PRE(B); q--;            // next quad's loads issue while A's are in flight
      CONSUME(A); aLive = false;
      if (q == 0) { CONSUME(B); break; }
      PRE(A); q--; aLive = true;
      CONSUME(B);
    }
    if (aLive) CONSUME(A);
  }

#undef PRE
#undef CONSUME
#undef ACC1
#undef LDSC
#undef LDF8

  // remainder (up to 15 edges): straight-line predicated, two-tier (proven)
  auto edgem = [&](unsigned off, bool valid) {
    unsigned o = valid ? off : begb;
    int nb = *(const int*)(colc + o);
    unsigned so = (LAYER == 1) ? (((unsigned)nb << 4) + ssh) : ((unsigned)nb << 1);
    float x = sself + __half2float(*(const __half*)(scc + so));
    int2 r = *(const int2*)(f8c + (((unsigned)nb << 6) + f8sh));
    float w = valid ? exp2f(-fmaxf(x, 0.2f * x)) : 0.f;
    wsum += w;
    f32x2 w2 = {w, w};
    acc2[0] += w2 * __builtin_amdgcn_cvt_pk_f32_fp8((unsigned)r.x, false);
    acc2[1] += w2 * __builtin_amdgcn_cvt_pk_f32_fp8((unsigned)r.x, true);
    acc2[2] += w2 * __builtin_amdgcn_cvt_pk_f32_fp8((unsigned)r.y, false);
    acc2[3] += w2 * __builtin_amdgcn_cvt_pk_f32_fp8((unsigned)r.y, true);
  };
  int rem = deg & 15;
  if (rem) {
    edgem(coff, g < rem);
    edgem(coff + 16, (4 + g) < rem);
    if (rem > 8) {
      edgem(coff + 32, (8 + g) < rem);
      edgem(coff + 48, (12 + g) < rem);
    }
  }

#pragma unroll
  for (int k = 0; k < 4; k++) {
    f32x2 t;
    t.x = __shfl_xor(acc2[k].x, 8);
    t.y = __shfl_xor(acc2[k].y, 8);
    acc2[k] += t;
    t.x = __shfl_xor(acc2[k].x, 16);
    t.y = __shfl_xor(acc2[k].y, 16);
    acc2[k] += t;
  }
  wsum += __shfl_xor(wsum, 8);
  wsum += __shfl_xor(wsum, 16);

  if (act) {
    float inv = (deg > 0) ? 1.f / (wsum * FP8_SCALE) : 0.f;
    f32x2 a2;
    if (g == 0) a2 = acc2[0];
    else if (g == 1) a2 = acc2[1];
    else if (g == 2) a2 = acc2[2];
    else a2 = acc2[3];
    float2 sf = __half22float2(selfh);
    float v0 = sf.x + a2.x * inv;
    float v1 = sf.y + a2.y * inv;
    v0 = (v0 > 0.f) ? v0 : (__expf(v0) - 1.f);
    v1 = (v1 > 0.f) ? v1 : (__expf(v1) - 1.f);
    *(__half2*)(fB + boff) = __floats2half2_rn(v0, v1);
  }
}

__global__ __launch_bounds__(256) void k_aggL1(
    const int* __restrict__ ptr, const int* __restrict__ col,
    const unsigned char* __restrict__ f8, const __half* __restrict__ fA,
    __half* __restrict__ fB, const __half* __restrict__ s16) {
  agg_body<1>(ptr, col, f8, fA, fB, s16, nullptr, nullptr);
}

__global__ __launch_bounds__(256) void k_aggL2(
    const int* __restrict__ ptr, const int* __restrict__ col,
    const unsigned char* __restrict__ f8, const __half* __restrict__ fA,
    __half* __restrict__ fB, const __half* __restrict__ s2,
    const int* __restrict__ list, const int* __restrict__ nm) {
  agg_body<2>(ptr, col, f8, fA, fB, s2, list, nm);
}

// ---------------- Final pair dot (fp16 inputs; 32 pairs/block, 8 lanes each) ----------
__global__ void k_dot(const int* __restrict__ uIdx, const int* __restrict__ iIdx,
                      const __half* __restrict__ u_f, const __half* __restrict__ i_f,
                      float* __restrict__ out) {
  int t = threadIdx.x;
  int pair = blockIdx.x * 32 + (t >> 3);
  int cc = t & 7;
  float4 ra = *(const float4*)(u_f + (size_t)uIdx[pair] * 64 + cc * 8);
  float4 rb = *(const float4*)(i_f + (size_t)iIdx[pair] * 64 + cc * 8);
  const __half* ha = (const __half*)&ra;
  const __half* hb = (const __half*)&rb;
  float v = 0.f;
#pragma unroll
  for (int k = 0; k < 8; k++) v += (float)ha[k] * (float)hb[k];
  v += __shfl_xor(v, 1);
  v += __shfl_xor(v, 2);
  v += __shfl_xor(v, 4);
  if (cc == 0) out[pair] = v;
}

extern "C" void kernel_launch(void* const* d_in, const int* in_sizes, int n_in,
                              void* d_out, int out_size, void* d_ws, size_t ws_size,
                              hipStream_t stream) {
  const int* userIdx = (const int*)d_in[0];
  const int* itemIdx = (const int*)d_in[1];
  const int* edge_u = (const int*)d_in[2];
  const int* edge_i = (const int*)d_in[3];
  const float* uEmbd = (const float*)d_in[4];
  const float* iEmbd = (const float*)d_in[5];
  const float* Wu_h = (const float*)d_in[6];
  const float* Wi_h = (const float*)d_in[7];
  const float* a_h = (const float*)d_in[8];
  const float* Wu_out = (const float*)d_in[9];
  const float* Wi_out = (const float*)d_in[10];
  const float* a_out = (const float*)d_in[11];
  float* out = (float*)d_out;

  char* w = (char*)d_ws;
  size_t off = 0;
  auto alloc = [&](size_t bytes) -> void* {
    void* p = w + off;
    off += (bytes + 511) & ~(size_t)511;
    return p;
  };
  // zero-init block: bcnt[NBK] | ecnt[NBK] | nm[16] | flag[UI_N] — one memset
  int* bcnt = (int*)alloc((size_t)(2 * NBK + 16 + UI_N) * 4);
  int* ecnt = bcnt + NBK;
  int* nm = bcnt + 2 * NBK;
  int* flag = bcnt + 2 * NBK + 16;
  int* ptr = (int*)alloc((size_t)(UI_N + 1) * 4);
  int* list = (int*)alloc((size_t)MAXACT * 4);
  int* col = (int*)alloc((size_t)COL_CAP * 4);
  __half* fA = (__half*)alloc((size_t)UI_N * 64 * 2);
  unsigned char* fA8 = (unsigned char*)alloc((size_t)UI_N * 64);
  __half* s16 = (__half*)alloc((size_t)UI_N * 8 * 2);
  __half* s2 = (__half*)alloc((size_t)UI_N * 2);
  size_t union_off = off;
  int* storage = (int*)alloc((size_t)NBK * CAP * 4);  // dead after k_fused2
  size_t end_storage = off;
  off = union_off;
  __half* fB = (__half*)alloc((size_t)UI_N * 64 * 2);
  if (off < end_storage) off = end_storage;

  hipMemsetAsync(bcnt, 0, (size_t)(2 * NBK + 16 + UI_N) * 4, stream);
  k_build1<<<NBLD, 1024, 0, stream>>>(edge_u, edge_i, bcnt, ecnt, storage);

  k_fused2<<<NBK + 64 + NB_U + NB_I, 256, 0, stream>>>(
      bcnt, ecnt, storage, ptr, col, userIdx, itemIdx, flag, list, nm,
      uEmbd, iEmbd, Wu_h, Wi_h, a_h, fA, fA8, s16);

  // Layer 1 aggregation over ALL nodes (8 nodes/block)
  k_aggL1<<<UI_N / 8, 256, 0, stream>>>(ptr, col, fA8, fA, fB, s16);

  k_mm2<<<NB_U + NB_I, 256, 0, stream>>>(fB, Wu_out, Wi_out, a_out, fA, fA8, s2, flag);
  k_aggL2<<<MAXACT / 8, 256, 0, stream>>>(ptr, col, fA8, fA, fB, s2, list, nm);

  k_dot<<<B_N / 32, 256, 0, stream>>>(userIdx, itemIdx, fB, fB + (size_t)U_N * 64, out);
}

// Round 14
// 269.608 us; speedup vs baseline: 1.0258x; 1.0258x over previous
//
#include <hip/hip_runtime.h>
#include <hip/hip_fp16.h>

#define U_N 50000
#define I_N 100000
#define E_N 1600000
#define B_N 16384
#define UI_N (U_N + I_N)   // 150000
#define NB_U 782           // ceil(50000/64)
#define NB_I 1563          // ceil(100000/64)
#define NBK 586            // ceil(150000/256) buckets, 256 nodes each
#define CAP 16384          // padded entries per bucket
#define NBLD 256           // blocks in k_build1 (proven round-5/9/12 config)
#define CHUNK (E_N / NBLD) // 6250 edges per block
#define COL_CAP 3300000    // compact col (exact 3.2M + margin)
#define MAXACT 32768       // max unique dot nodes
#define FP8_SCALE 128.0f
#define LOG2E 1.44269504088896f

typedef float f32x2 __attribute__((ext_vector_type(2)));

// ---------------- CSR build phase 1: LDS counting-sort + full-line burst writes -------
// R12-proven. No per-edge global atomics (R7/R11 lessons: device-scope atomics are
// memory-side RMW on this chip at ~30us per million — forbidden at edge scale).
__global__ __launch_bounds__(1024) void k_build1(
    const int* __restrict__ eu, const int* __restrict__ ei,
    int* __restrict__ bcnt, int* __restrict__ ecnt, int* __restrict__ storage) {
  __shared__ int hist[NBK];
  __shared__ int pb16[NBK];
  __shared__ int gbase[NBK];
  __shared__ int loff[NBK];
  __shared__ short map16[1344];
  __shared__ int sc[1024];
  __shared__ int sorted[21504];
  int t = threadIdx.x;
  for (int b = t; b < NBK; b += 1024) { hist[b] = 0; loff[b] = 0; }
  __syncthreads();
  int e0 = blockIdx.x * CHUNK;
  int myu[7], myi[7];
#pragma unroll
  for (int k = 0; k < 7; k++) {
    myu[k] = -1;
    if (t + 1024 * k < CHUNK) {
      int e = e0 + t + 1024 * k;
      int u = eu[e], it = ei[e];
      myu[k] = u;
      myi[k] = it;
      atomicAdd(&hist[u >> 8], 1);
      atomicAdd(&hist[(U_N + it) >> 8], 1);
    }
  }
  __syncthreads();
  int ph = (t < NBK) ? ((hist[t] + 15) & ~15) : 0;
  sc[t] = ph;
  __syncthreads();
  int val = ph;
  for (int o = 1; o < 1024; o <<= 1) {
    int x = (t >= o) ? sc[t - o] : 0;
    __syncthreads();
    val += x;
    sc[t] = val;
    __syncthreads();
  }
  int total16 = sc[1023];
  if (t < NBK) {
    int myb = val - ph;
    pb16[t] = myb;
    gbase[t] = ph ? atomicAdd(&bcnt[t], ph) : 0;
    if (hist[t]) atomicAdd(&ecnt[t], hist[t]);
    for (int k = myb >> 4; k < (myb + ph) >> 4; k++) map16[k] = (short)t;
  }
  for (int j = t; j < total16; j += 1024) sorted[j] = -1;
  __syncthreads();
#pragma unroll
  for (int k = 0; k < 7; k++) {
    if (myu[k] >= 0) {
      int u = myu[k], it = myi[k];
      int k2 = U_N + it;
      int b1 = u >> 8;
      int p1 = pb16[b1] + atomicAdd(&loff[b1], 1);
      sorted[p1] = ((u & 255) << 18) | k2;
      int b2 = k2 >> 8;
      int p2 = pb16[b2] + atomicAdd(&loff[b2], 1);
      sorted[p2] = ((k2 & 255) << 18) | u;
    }
  }
  __syncthreads();
  for (int j = t; j < total16; j += 1024) {
    int b = map16[j >> 4];
    storage[(size_t)b * CAP + gbase[b] + (j - pb16[b])] = sorted[j];
  }
}

// ---- CSR build phase 2: count (skip sentinels) -> LDS prefix -> LDS-staged scatter
//      -> coalesced burst copy to global col (R12-proven) ----
__device__ void build2_body(int b, const int* __restrict__ bcnt,
                            const int* __restrict__ ecnt,
                            const int* __restrict__ storage,
                            int* __restrict__ ptr, int* __restrict__ col,
                            int* smem) {
  int* c = smem;            // [256]
  int* sc = smem + 256;     // [256]
  int* pbl = smem + 512;    // [256]
  int* cur = smem + 768;    // [256]
  int* tot = smem + 1024;   // [1]
  int* lcol = smem + 1040;  // [10240]
  int t = threadIdx.x;
  int pre = 0;
  for (int i = t; i < b; i += 256) pre += ecnt[i];
  sc[t] = pre;
  c[t] = 0;
  __syncthreads();
  for (int o = 128; o > 0; o >>= 1) {
    if (t < o) sc[t] += sc[t + o];
    __syncthreads();
  }
  int base = sc[0];
  __syncthreads();
  int n = bcnt[b];
  const int* s = storage + (size_t)b * CAP;
  for (int i = t; i < n; i += 256) {
    int e = s[i];
    if (e >= 0) atomicAdd(&c[e >> 18], 1);
  }
  __syncthreads();
  int deg = c[t];
  sc[t] = deg;
  __syncthreads();
  int val = deg;
  for (int o = 1; o < 256; o <<= 1) {
    int x = (t >= o) ? sc[t - o] : 0;
    __syncthreads();
    val += x;
    sc[t] = val;
    __syncthreads();
  }
  int myoff = val - deg;
  pbl[t] = myoff;
  cur[t] = 0;
  if (t == 255) tot[0] = val;
  int node = b * 256 + t;
  if (node < UI_N) ptr[node] = base + myoff;
  if (b == NBK - 1 && t == 255) ptr[UI_N] = base + val;
  __syncthreads();
  for (int i = t; i < n; i += 256) {
    int e = s[i];
    if (e >= 0) {
      int local = e >> 18;
      int pos = pbl[local] + atomicAdd(&cur[local], 1);
      lcol[pos] = e & 0x3FFFF;
    }
  }
  __syncthreads();
  int vt = tot[0];
  for (int i = t; i < vt; i += 256) col[base + i] = lcol[i];
}

// ---------------- active-node flag + compaction body ----------------
__device__ __forceinline__ void flagc_body(int bid, const int* __restrict__ uIdx,
                                           const int* __restrict__ iIdx,
                                           int* __restrict__ flag, int* __restrict__ list,
                                           int* __restrict__ nm) {
  int b = bid * 256 + threadIdx.x;
  if (b < B_N) {
    int u = uIdx[b];
    if (atomicExch(&flag[u], 1) == 0) list[atomicAdd(nm, 1)] = u;
    int it = U_N + iIdx[b];
    if (atomicExch(&flag[it], 1) == 0) list[atomicAdd(nm, 1)] = it;
  }
}

// ---------------- Fused matmul + attention scores body (fp16 + fp8 outputs) ----------
// Scores stored pre-scaled by log2(e) -> agg uses bare exp2 per edge.
__device__ __forceinline__ void mm2_body(
    int bid, const float* __restrict__ Xu32, const float* __restrict__ Xi32,
    const __half* __restrict__ X16,
    const float* __restrict__ Wu, const float* __restrict__ Wi,
    const float* __restrict__ a, int layer,
    __half* __restrict__ f16, unsigned char* __restrict__ f8,
    __half* __restrict__ s16, const int* __restrict__ flagp,
    float* Wl, float* Xs) {
  const bool isU = bid < NB_U;
  const int N = isU ? U_N : I_N;
  const int base = (isU ? bid : bid - NB_U) * 64;
  const int gofs = isU ? 0 : U_N;
  const float* W = isU ? Wu : Wi;
  const int aoff = (layer == 1) ? (isU ? 0 : 8) : (isU ? 0 : 64);
  int t = threadIdx.x;

  if (layer == 1) {
#pragma unroll
    for (int k = 0; k < 4; k++) {
      int i = t + 256 * k;
      int h = i >> 7, d = (i >> 1) & 63, half = i & 1;
      float4 v = *(const float4*)(W + h * 512 + d * 8 + half * 4);
      *(float4*)(Wl + d * 64 + h * 8 + half * 4) = v;
    }
    const float* X = isU ? Xu32 : Xi32;
#pragma unroll
    for (int k = 0; k < 4; k++) {
      int i = t + 256 * k;
      int r = i >> 4, ch = i & 15;
      int node = base + r;
      float4 v = make_float4(0.f, 0.f, 0.f, 0.f);
      if (node < N) v = *(const float4*)(X + (size_t)node * 64 + ch * 4);
      *(float4*)(Xs + r * 64 + ch * 4) = v;
    }
  } else {
#pragma unroll
    for (int k = 0; k < 4; k++) {
      int i = t + 256 * k;
      *(float4*)(Wl + i * 4) = *(const float4*)(W + i * 4);
    }
#pragma unroll
    for (int k = 0; k < 4; k++) {
      int i = t + 256 * k;
      int r = i >> 4, ch = i & 15;
      int node = base + r;
      float4 v = make_float4(0.f, 0.f, 0.f, 0.f);
      if (node < N) {
        const __half2* hp = (const __half2*)(X16 + (size_t)(gofs + node) * 64 + ch * 4);
        float2 f0 = __half22float2(hp[0]);
        float2 f1 = __half22float2(hp[1]);
        v = make_float4(f0.x, f0.y, f1.x, f1.y);
      }
      *(float4*)(Xs + r * 64 + ch * 4) = v;
    }
  }
  __syncthreads();

  const int c0 = t & 31;
  const int rb = t >> 5;
  float acc0[8], acc1[8];
#pragma unroll
  for (int k = 0; k < 8; k++) { acc0[k] = 0.f; acc1[k] = 0.f; }

  for (int d0 = 0; d0 < 64; d0 += 4) {
    float2 wA = *(float2*)(Wl + (d0 + 0) * 64 + 2 * c0);
    float2 wB = *(float2*)(Wl + (d0 + 1) * 64 + 2 * c0);
    float2 wC = *(float2*)(Wl + (d0 + 2) * 64 + 2 * c0);
    float2 wD = *(float2*)(Wl + (d0 + 3) * 64 + 2 * c0);
#pragma unroll
    for (int k = 0; k < 8; k++) {
      float4 x = *(float4*)(Xs + (rb + 8 * k) * 64 + d0);
      acc0[k] += x.x * wA.x + x.y * wB.x + x.z * wC.x + x.w * wD.x;
      acc1[k] += x.x * wA.y + x.y * wB.y + x.z * wC.y + x.w * wD.y;
    }
  }

  float av0, av1;
  if (layer == 1) {
    int h = c0 >> 2, j = 2 * (c0 & 3);
    av0 = a[h * 16 + aoff + j];
    av1 = a[h * 16 + aoff + j + 1];
  } else {
    av0 = a[aoff + 2 * c0];
    av1 = a[aoff + 2 * c0 + 1];
  }
#pragma unroll
  for (int k = 0; k < 8; k++) {
    int node = base + rb + 8 * k;
    float s = acc0[k] * av0 + acc1[k] * av1;
    s += __shfl_xor(s, 1);
    s += __shfl_xor(s, 2);
    if (layer != 1) {
      s += __shfl_xor(s, 4);
      s += __shfl_xor(s, 8);
      s += __shfl_xor(s, 16);
    }
    if (node < N) {
      int gn = gofs + node;
      if (layer == 1 || flagp[gn]) {
        float2 f;
        f.x = acc0[k];
        f.y = acc1[k];
        *(__half2*)(f16 + (size_t)gn * 64 + 2 * c0) = __float22half2_rn(f);
      }
      int pk = __builtin_amdgcn_cvt_pk_fp8_f32(acc0[k] * FP8_SCALE,
                                               acc1[k] * FP8_SCALE, 0, false);
      *(unsigned short*)(f8 + (size_t)gn * 64 + 2 * c0) = (unsigned short)pk;
      if (layer == 1) {
        if ((c0 & 3) == 0) s16[gn * 8 + (c0 >> 2)] = __float2half_rn(s * LOG2E);
      } else {
        if (c0 == 0) s16[gn] = __float2half_rn(s * LOG2E);
      }
    }
  }
}

// ---- Fused dispatch: build2 (+count) | flagc | mm2-L1, all 256-thread blocks ---------
__global__ __launch_bounds__(256) void k_fused2(
    const int* __restrict__ bcnt, const int* __restrict__ ecnt,
    const int* __restrict__ storage,
    int* __restrict__ ptr, int* __restrict__ col,
    const int* __restrict__ uIdx, const int* __restrict__ iIdx,
    int* __restrict__ flag, int* __restrict__ list, int* __restrict__ nm,
    const float* __restrict__ uEmbd, const float* __restrict__ iEmbd,
    const float* __restrict__ Wu, const float* __restrict__ Wi,
    const float* __restrict__ a, __half* __restrict__ fA,
    unsigned char* __restrict__ fA8, __half* __restrict__ s16) {
  __shared__ __align__(16) int smem_i[11296];  // 45.2KB: build2 stage / mm 8192 floats
  int bx = blockIdx.x;
  if (bx < NBK) {
    build2_body(bx, bcnt, ecnt, storage, ptr, col, smem_i);
  } else if (bx < NBK + 64) {
    flagc_body(bx - NBK, uIdx, iIdx, flag, list, nm);
  } else {
    float* s = (float*)smem_i;
    mm2_body(bx - NBK - 64, uEmbd, iEmbd, nullptr, Wu, Wi, a, 1, fA, fA8, s16,
             nullptr, s, s + 4096);
  }
}

// ---------------- Layer-2 matmul (standalone) ----------------
__global__ __launch_bounds__(256) void k_mm2(
    const __half* __restrict__ X16, const float* __restrict__ Wu,
    const float* __restrict__ Wi, const float* __restrict__ a,
    __half* __restrict__ f16, unsigned char* __restrict__ f8,
    __half* __restrict__ s2, const int* __restrict__ flag) {
  __shared__ __align__(16) float smv[8192];
  mm2_body(blockIdx.x, nullptr, nullptr, X16, Wu, Wi, a, 2, f16, f8, s2, flag,
           smv, smv + 4096);
}

// ---------------- Fused aggregation: TWO nodes/wave, 8 nodes/block (local optimum) ---
// VERIFIED LOCAL OPTIMUM (R6/R12/R13): 32 VGPR = exactly the 8-wave/SIMD boundary;
// any ILP addition (+regs) drops waves 8->6 and loses more than it gains. Kernel is
// concurrency-bound (outstanding misses/CU); FETCH at the x8-XCD compulsory floor.
template <int LAYER>
__device__ __forceinline__ void agg_body(
    const int* __restrict__ ptr, const int* __restrict__ col,
    const unsigned char* __restrict__ f8,  // [UI_N][64] e4m3 x128
    const __half* __restrict__ fA,         // [UI_N][64] fp16 (self)
    __half* __restrict__ fB,               // [UI_N][64]
    const __half* __restrict__ sc,         // L1: [UI_N][8] (xlog2e); L2: [UI_N] (xlog2e)
    const int* __restrict__ list, const int* __restrict__ nm) {
  int gid = blockIdx.x * blockDim.x + threadIdx.x;
  int wv = gid >> 6;
  int l = threadIdx.x & 63;
  int half = l >> 5;
  int idx = wv * 2 + half;
  bool act = true;
  int n;
  if (LAYER == 2) {
    act = idx < *nm;
    n = act ? list[idx] : 0;
  } else {
    n = idx;
  }
  int lh = l & 31;
  int g = lh >> 3;
  int cc = lh & 7;

  int beg = ptr[n], endA = ptr[n + 1];
  int deg = act ? (endA - beg) : 0;
  unsigned coff = ((unsigned)(beg + g)) << 2;
  const unsigned begb = (unsigned)beg << 2;
  const unsigned f8sh = (unsigned)cc << 3;
  const unsigned ssh = (LAYER == 1) ? ((unsigned)cc << 1) : 0u;
  float sself = (LAYER == 1) ? __half2float(sc[(size_t)n * 8 + cc])
                             : __half2float(sc[n]);
  f32x2 acc2[4];
#pragma unroll
  for (int k = 0; k < 4; k++) acc2[k] = (f32x2){0.f, 0.f};
  float wsum = 0.f;
  const char* colc = (const char*)col;
  const char* f8c = (const char*)f8;
  const char* scc = (const char*)sc;

  auto edge = [&](unsigned off) {
    int nb = *(const int*)(colc + off);
    unsigned so = (LAYER == 1) ? (((unsigned)nb << 4) + ssh) : ((unsigned)nb << 1);
    float x = sself + __half2float(*(const __half*)(scc + so));
    int2 r = *(const int2*)(f8c + (((unsigned)nb << 6) + f8sh));
    float w = exp2f(-fmaxf(x, 0.2f * x));
    wsum += w;
    f32x2 w2 = {w, w};
    acc2[0] += w2 * __builtin_amdgcn_cvt_pk_f32_fp8((unsigned)r.x, false);
    acc2[1] += w2 * __builtin_amdgcn_cvt_pk_f32_fp8((unsigned)r.x, true);
    acc2[2] += w2 * __builtin_amdgcn_cvt_pk_f32_fp8((unsigned)r.y, false);
    acc2[3] += w2 * __builtin_amdgcn_cvt_pk_f32_fp8((unsigned)r.y, true);
  };
  auto edgem = [&](unsigned off, bool valid) {
    unsigned o = valid ? off : begb;
    int nb = *(const int*)(colc + o);
    unsigned so = (LAYER == 1) ? (((unsigned)nb << 4) + ssh) : ((unsigned)nb << 1);
    float x = sself + __half2float(*(const __half*)(scc + so));
    int2 r = *(const int2*)(f8c + (((unsigned)nb << 6) + f8sh));
    float w = valid ? exp2f(-fmaxf(x, 0.2f * x)) : 0.f;
    wsum += w;
    f32x2 w2 = {w, w};
    acc2[0] += w2 * __builtin_amdgcn_cvt_pk_f32_fp8((unsigned)r.x, false);
    acc2[1] += w2 * __builtin_amdgcn_cvt_pk_f32_fp8((unsigned)r.x, true);
    acc2[2] += w2 * __builtin_amdgcn_cvt_pk_f32_fp8((unsigned)r.y, false);
    acc2[3] += w2 * __builtin_amdgcn_cvt_pk_f32_fp8((unsigned)r.y, true);
  };

  int q = deg >> 4;
  for (; q > 0; q--) {
    edge(coff);
    edge(coff + 16);
    edge(coff + 32);
    edge(coff + 48);
    coff += 64;
  }
  int rem = deg & 15;
  if (rem) {
    edgem(coff, g < rem);
    edgem(coff + 16, (4 + g) < rem);
    if (rem > 8) {
      edgem(coff + 32, (8 + g) < rem);
      edgem(coff + 48, (12 + g) < rem);
    }
  }

#pragma unroll
  for (int k = 0; k < 4; k++) {
    f32x2 t;
    t.x = __shfl_xor(acc2[k].x, 8);
    t.y = __shfl_xor(acc2[k].y, 8);
    acc2[k] += t;
    t.x = __shfl_xor(acc2[k].x, 16);
    t.y = __shfl_xor(acc2[k].y, 16);
    acc2[k] += t;
  }
  wsum += __shfl_xor(wsum, 8);
  wsum += __shfl_xor(wsum, 16);

  if (act) {
    float inv = (deg > 0) ? 1.f / (wsum * FP8_SCALE) : 0.f;
    f32x2 a2;
    if (g == 0) a2 = acc2[0];
    else if (g == 1) a2 = acc2[1];
    else if (g == 2) a2 = acc2[2];
    else a2 = acc2[3];
    size_t boff = (size_t)n * 64 + cc * 8 + 2 * g;
    float2 sf = __half22float2(*(const __half2*)(fA + boff));
    float v0 = sf.x + a2.x * inv;
    float v1 = sf.y + a2.y * inv;
    v0 = (v0 > 0.f) ? v0 : (__expf(v0) - 1.f);
    v1 = (v1 > 0.f) ? v1 : (__expf(v1) - 1.f);
    *(__half2*)(fB + boff) = __floats2half2_rn(v0, v1);
  }
}

__global__ __launch_bounds__(256) void k_aggL1(
    const int* __restrict__ ptr, const int* __restrict__ col,
    const unsigned char* __restrict__ f8, const __half* __restrict__ fA,
    __half* __restrict__ fB, const __half* __restrict__ s16) {
  agg_body<1>(ptr, col, f8, fA, fB, s16, nullptr, nullptr);
}

__global__ __launch_bounds__(256) void k_aggL2(
    const int* __restrict__ ptr, const int* __restrict__ col,
    const unsigned char* __restrict__ f8, const __half* __restrict__ fA,
    __half* __restrict__ fB, const __half* __restrict__ s2,
    const int* __restrict__ list, const int* __restrict__ nm) {
  agg_body<2>(ptr, col, f8, fA, fB, s2, list, nm);
}

// ---------------- Final pair dot (fp16 inputs; 32 pairs/block, 8 lanes each) ----------
__global__ void k_dot(const int* __restrict__ uIdx, const int* __restrict__ iIdx,
                      const __half* __restrict__ u_f, const __half* __restrict__ i_f,
                      float* __restrict__ out) {
  int t = threadIdx.x;
  int pair = blockIdx.x * 32 + (t >> 3);
  int cc = t & 7;
  float4 ra = *(const float4*)(u_f + (size_t)uIdx[pair] * 64 + cc * 8);
  float4 rb = *(const float4*)(i_f + (size_t)iIdx[pair] * 64 + cc * 8);
  const __half* ha = (const __half*)&ra;
  const __half* hb = (const __half*)&rb;
  float v = 0.f;
#pragma unroll
  for (int k = 0; k < 8; k++) v += (float)ha[k] * (float)hb[k];
  v += __shfl_xor(v, 1);
  v += __shfl_xor(v, 2);
  v += __shfl_xor(v, 4);
  if (cc == 0) out[pair] = v;
}

extern "C" void kernel_launch(void* const* d_in, const int* in_sizes, int n_in,
                              void* d_out, int out_size, void* d_ws, size_t ws_size,
                              hipStream_t stream) {
  const int* userIdx = (const int*)d_in[0];
  const int* itemIdx = (const int*)d_in[1];
  const int* edge_u = (const int*)d_in[2];
  const int* edge_i = (const int*)d_in[3];
  const float* uEmbd = (const float*)d_in[4];
  const float* iEmbd = (const float*)d_in[5];
  const float* Wu_h = (const float*)d_in[6];
  const float* Wi_h = (const float*)d_in[7];
  const float* a_h = (const float*)d_in[8];
  const float* Wu_out = (const float*)d_in[9];
  const float* Wi_out = (const float*)d_in[10];
  const float* a_out = (const float*)d_in[11];
  float* out = (float*)d_out;

  char* w = (char*)d_ws;
  size_t off = 0;
  auto alloc = [&](size_t bytes) -> void* {
    void* p = w + off;
    off += (bytes + 511) & ~(size_t)511;
    return p;
  };
  // zero-init block: bcnt[NBK] | ecnt[NBK] | nm[16] | flag[UI_N] — one memset
  int* bcnt = (int*)alloc((size_t)(2 * NBK + 16 + UI_N) * 4);
  int* ecnt = bcnt + NBK;
  int* nm = bcnt + 2 * NBK;
  int* flag = bcnt + 2 * NBK + 16;
  int* ptr = (int*)alloc((size_t)(UI_N + 1) * 4);
  int* list = (int*)alloc((size_t)MAXACT * 4);
  int* col = (int*)alloc((size_t)COL_CAP * 4);
  __half* fA = (__half*)alloc((size_t)UI_N * 64 * 2);
  unsigned char* fA8 = (unsigned char*)alloc((size_t)UI_N * 64);
  __half* s16 = (__half*)alloc((size_t)UI_N * 8 * 2);
  __half* s2 = (__half*)alloc((size_t)UI_N * 2);
  size_t union_off = off;
  int* storage = (int*)alloc((size_t)NBK * CAP * 4);  // dead after k_fused2
  size_t end_storage = off;
  off = union_off;
  __half* fB = (__half*)alloc((size_t)UI_N * 64 * 2);
  if (off < end_storage) off = end_storage;

  hipMemsetAsync(bcnt, 0, (size_t)(2 * NBK + 16 + UI_N) * 4, stream);
  k_build1<<<NBLD, 1024, 0, stream>>>(edge_u, edge_i, bcnt, ecnt, storage);

  k_fused2<<<NBK + 64 + NB_U + NB_I, 256, 0, stream>>>(
      bcnt, ecnt, storage, ptr, col, userIdx, itemIdx, flag, list, nm,
      uEmbd, iEmbd, Wu_h, Wi_h, a_h, fA, fA8, s16);

  // Layer 1 aggregation over ALL nodes (8 nodes/block)
  k_aggL1<<<UI_N / 8, 256, 0, stream>>>(ptr, col, fA8, fA, fB, s16);

  k_mm2<<<NB_U + NB_I, 256, 0, stream>>>(fB, Wu_out, Wi_out, a_out, fA, fA8, s2, flag);
  k_aggL2<<<MAXACT / 8, 256, 0, stream>>>(ptr, col, fA8, fA, fB, s2, list, nm);

  k_dot<<<B_N / 32, 256, 0, stream>>>(userIdx, itemIdx, fB, fB + (size_t)U_N * 64, out);
}